// Round 1
// baseline (580.600 us; speedup 1.0000x reference)
//
#include <hip/hip_runtime.h>

#define B 8
#define C 4
#define H 384
#define W 384
#define HW (H * W)
#define CHW (C * H * W)
#define NTOT (B * CHW)      // 4,718,592
#define BIGD 768            // H + W sentinel, matches reference

// ---------------- ws layout ----------------
// [0, NTOT) floats        : g2, overwritten in-place by dt
// offset NTOT*4           : 32 uints (per-slice dmax as float bits)
// offset NTOT*4 + 128     : 1 double (loss sum)
#define DMAX_OFF (NTOT * 4)
#define SUM_OFF  (NTOT * 4 + 128)

__global__ void init_kernel(unsigned int* dmax, double* sum) {
    int t = threadIdx.x;
    if (t < B * C) dmax[t] = 0u;
    if (t == 0) *sum = 0.0;
}

// One thread per (b,c,w) column: vertical 1D distance, store g^2 as float.
__global__ void edt_vertical(const int* __restrict__ targets, float* __restrict__ g2) {
    int idx = blockIdx.x * blockDim.x + threadIdx.x;
    if (idx >= B * C * W) return;
    int w = idx % W;
    int c = (idx / W) % C;
    int b = idx / (W * C);

    const int* t = targets + b * HW + w;
    float* g = g2 + (size_t)b * CHW + (size_t)c * HW + w;

    int d = BIGD;
    for (int h = 0; h < H; ++h) {
        int z = (t[h * W] == c);
        d = z ? 0 : min(d + 1, BIGD);
        g[h * W] = (float)d;               // stash forward distance
    }
    d = BIGD;
    for (int h = H - 1; h >= 0; --h) {
        int z = (t[h * W] == c);
        d = z ? 0 : min(d + 1, BIGD);
        float f = g[h * W];
        float m = fminf(f, (float)d);
        g[h * W] = m * m;                  // final vertical squared distance
    }
}

// One block per (b,c,h) row: dt[w] = sqrt(min_j g2[j] + (w-j)^2), in place.
// Also block-max -> atomicMax into per-slice dmax (uint bits, dt >= 0).
__global__ void edt_horizontal(float* __restrict__ g2, unsigned int* __restrict__ dmax) {
    __shared__ float row[W];
    __shared__ float wmax[2];
    int r = blockIdx.x;                     // ((b*C + c)*H + h)
    float* gr = g2 + (size_t)r * W;

    for (int j = threadIdx.x; j < W; j += 128) row[j] = gr[j];
    __syncthreads();

    float res[3];
    float lmax = 0.0f;
    #pragma unroll
    for (int k = 0; k < 3; ++k) {
        int w = threadIdx.x + k * 128;
        float best = 3.0e38f;
        for (int j = 0; j < W; ++j) {
            float dy = (float)(w - j);
            best = fminf(best, row[j] + dy * dy);
        }
        float dt = sqrtf(best);
        res[k] = dt;
        lmax = fmaxf(lmax, dt);
    }
    #pragma unroll
    for (int k = 0; k < 3; ++k) gr[threadIdx.x + k * 128] = res[k];

    // block max reduction (128 threads = 2 waves)
    #pragma unroll
    for (int off = 32; off > 0; off >>= 1)
        lmax = fmaxf(lmax, __shfl_down(lmax, off));
    int lane = threadIdx.x & 63, wv = threadIdx.x >> 6;
    if (lane == 0) wmax[wv] = lmax;
    __syncthreads();
    if (threadIdx.x == 0) {
        float m = fmaxf(wmax[0], wmax[1]);
        atomicMax(&dmax[r / H], __float_as_uint(m));
    }
}

// Grid-stride over pixels: softmax * dist_map, double accumulate, atomicAdd.
__global__ void reduce_loss(const float* __restrict__ outputs,
                            const int* __restrict__ targets,
                            const float* __restrict__ dt,
                            const unsigned int* __restrict__ dmax,
                            double* __restrict__ sum) {
    double acc = 0.0;
    const int n = B * HW;
    for (int p = blockIdx.x * blockDim.x + threadIdx.x; p < n;
         p += gridDim.x * blockDim.x) {
        int b = p / HW;
        int hw = p - b * HW;
        const float* o = outputs + (size_t)b * CHW + hw;
        const float* d = dt + (size_t)b * CHW + hw;
        int t = targets[p];

        float o0 = o[0], o1 = o[HW], o2 = o[2 * HW], o3 = o[3 * HW];
        float m = fmaxf(fmaxf(o0, o1), fmaxf(o2, o3));
        float e0 = expf(o0 - m), e1 = expf(o1 - m), e2 = expf(o2 - m), e3 = expf(o3 - m);
        float inv = 1.0f / (e0 + e1 + e2 + e3);

        float d0 = (t == 0) ? -__uint_as_float(dmax[b * C + 0]) : d[0];
        float d1 = (t == 1) ? -__uint_as_float(dmax[b * C + 1]) : d[HW];
        float d2 = (t == 2) ? -__uint_as_float(dmax[b * C + 2]) : d[2 * HW];
        float d3 = (t == 3) ? -__uint_as_float(dmax[b * C + 3]) : d[3 * HW];

        float v = (e0 * d0 + e1 * d1 + e2 * d2 + e3 * d3) * inv;
        acc += (double)v;
    }
    // block reduce (256 threads = 4 waves)
    #pragma unroll
    for (int off = 32; off > 0; off >>= 1)
        acc += __shfl_down(acc, off);
    __shared__ double sacc[4];
    int lane = threadIdx.x & 63, wv = threadIdx.x >> 6;
    if (lane == 0) sacc[wv] = acc;
    __syncthreads();
    if (threadIdx.x == 0) {
        atomicAdd(sum, sacc[0] + sacc[1] + sacc[2] + sacc[3]);
    }
}

__global__ void finalize(const double* __restrict__ sum, float* __restrict__ out) {
    if (threadIdx.x == 0) {
        // divide by num_classes (C) and by element count (B*C*H*W)
        out[0] = (float)(*sum / (double)((double)C * (double)NTOT));
    }
}

extern "C" void kernel_launch(void* const* d_in, const int* in_sizes, int n_in,
                              void* d_out, int out_size, void* d_ws, size_t ws_size,
                              hipStream_t stream) {
    const float* outputs = (const float*)d_in[0];
    const int* targets = (const int*)d_in[1];
    float* out = (float*)d_out;

    float* g2 = (float*)d_ws;
    unsigned int* dmax = (unsigned int*)((char*)d_ws + DMAX_OFF);
    double* sum = (double*)((char*)d_ws + SUM_OFF);

    init_kernel<<<1, 64, 0, stream>>>(dmax, sum);

    int cols = B * C * W;  // 12288
    edt_vertical<<<(cols + 255) / 256, 256, 0, stream>>>(targets, g2);

    int rows = B * C * H;  // 12288
    edt_horizontal<<<rows, 128, 0, stream>>>(g2, dmax);

    reduce_loss<<<256, 256, 0, stream>>>(outputs, targets, g2, dmax, sum);

    finalize<<<1, 64, 0, stream>>>(sum, out);
}

// Round 2
// 284.475 us; speedup vs baseline: 2.0410x; 2.0410x over previous
//
#include <hip/hip_runtime.h>

#define B 8
#define C 4
#define H 384
#define W 384
#define HW (H * W)
#define CHW (C * H * W)
#define NTOT (B * CHW)      // 4,718,592
#define BIGD 768

// ---------------- ws layout ----------------
// [0, NTOT) floats : g2 (vertical squared distances; dt kept in registers)
// DMAX_OFF         : 32 uints (per-slice dmax as float bits)
// A_OFF            : 64 doubles (non-target loss partial sums, contention-spread)
// T_OFF            : 32 doubles (per-slice sum of softmax_c over target pixels)
#define DMAX_OFF (NTOT * 4)
#define A_OFF    (NTOT * 4 + 256)
#define T_OFF    (A_OFF + 64 * 8)

__global__ void init_kernel(unsigned int* dmax, double* A, double* T) {
    int t = threadIdx.x;
    if (t < B * C) { dmax[t] = 0u; T[t] = 0.0; }
    A[t] = 0.0;
}

// One thread per (b,c,w) column: vertical 1D distance, store g^2 as float.
// Backward pass detects feature pixels via (fwd==0) -> no target re-read.
__global__ __launch_bounds__(64) void edt_vertical(const int* __restrict__ targets,
                                                   float* __restrict__ g2) {
    int idx = blockIdx.x * 64 + threadIdx.x;
    int w = idx % W;
    int c = (idx / W) % C;
    int b = idx / (W * C);

    const int* t = targets + b * HW + w;
    float* g = g2 + (size_t)b * CHW + (size_t)c * HW + w;

    float d = (float)BIGD;
    #pragma unroll 4
    for (int h = 0; h < H; ++h) {
        int z = (t[h * W] == c);
        d = z ? 0.0f : fminf(d + 1.0f, (float)BIGD);
        g[h * W] = d;                      // stash forward distance
    }
    d = (float)BIGD;
    #pragma unroll 4
    for (int h = H - 1; h >= 0; --h) {
        float f = g[h * W];
        d = (f == 0.0f) ? 0.0f : fminf(d + 1.0f, (float)BIGD);
        float m = fminf(f, d);
        g[h * W] = m * m;                  // final vertical squared distance
    }
}

// One block (64 threads) per (b,c,h) row.
//  dt[w] = sqrt(min_j g2[j] + (w-j)^2)   -- shifted form: min_j (j^2+g2[j] + A_k j) + w^2
//  Fused: per-slice dmax atomicMax, and the loss reduction:
//    A += sum over non-target pixels of softmax_c * dt
//    T[slice] += sum over target pixels of softmax_c   (dmax applied in finalize)
__global__ __launch_bounds__(64) void edt_horiz_fused(
        const float* __restrict__ outputs, const int* __restrict__ targets,
        const float* __restrict__ g2, unsigned int* __restrict__ dmax,
        double* __restrict__ A, double* __restrict__ T) {
    __shared__ float row[W];
    int r = blockIdx.x;                     // ((b*C + c)*H + h)
    int h = r % H;
    int c = (r / H) % C;
    int b = r / (C * H);
    int tid = threadIdx.x;
    const float* gr = g2 + (size_t)r * W;

    {   // stage row into LDS with float4 loads
        const float4* g4 = (const float4*)gr;
        float4* r4 = (float4*)row;
        for (int j = tid; j < W / 4; j += 64) r4[j] = g4[j];
    }
    __syncthreads();

    float bs[6], Ak[6], W2k[6];
    #pragma unroll
    for (int k = 0; k < 6; ++k) {
        float wk = (float)(tid + 64 * k);
        Ak[k] = -2.0f * wk;
        W2k[k] = wk * wk;
        bs[k] = 3.0e38f;
    }
    for (int j = 0; j < W; j += 4) {
        float4 rv = *(const float4*)(row + j);   // uniform addr -> broadcast b128
        #pragma unroll
        for (int u = 0; u < 4; ++u) {
            float jf = (float)j + (float)u;
            float rvu = (u == 0) ? rv.x : (u == 1) ? rv.y : (u == 2) ? rv.z : rv.w;
            float sj = fmaf(jf, jf, rvu);        // j^2 + g2[j], exact int < 2^24
            #pragma unroll
            for (int k = 0; k < 6; ++k)
                bs[k] = fminf(bs[k], fmaf(Ak[k], jf, sj));
        }
    }
    float dt[6];
    float lmax = 0.0f;
    #pragma unroll
    for (int k = 0; k < 6; ++k) {
        dt[k] = sqrtf(bs[k] + W2k[k]);           // exact int sum, single sqrt round
        lmax = fmaxf(lmax, dt[k]);
    }
    #pragma unroll
    for (int off = 32; off > 0; off >>= 1)
        lmax = fmaxf(lmax, __shfl_down(lmax, off));
    if (tid == 0) atomicMax(&dmax[r / H], __float_as_uint(lmax));

    // ---- fused loss terms for this row / class c ----
    const float* ob = outputs + (size_t)b * CHW + (size_t)h * W;
    const int* tb = targets + (size_t)b * HW + (size_t)h * W;
    float a_acc = 0.0f, t_acc = 0.0f;
    #pragma unroll
    for (int k = 0; k < 6; ++k) {
        int w = tid + 64 * k;
        float o0 = ob[w], o1 = ob[HW + w], o2 = ob[2 * HW + w], o3 = ob[3 * HW + w];
        float m = fmaxf(fmaxf(o0, o1), fmaxf(o2, o3));
        float e0 = expf(o0 - m), e1 = expf(o1 - m), e2 = expf(o2 - m), e3 = expf(o3 - m);
        float sum = e0 + e1 + e2 + e3;
        float ec = (c == 0) ? e0 : (c == 1) ? e1 : (c == 2) ? e2 : e3;
        float p = ec / sum;
        int t = tb[w];
        if (t == c) t_acc += p;
        else        a_acc += p * dt[k];
    }
    double a_d = (double)a_acc, t_d = (double)t_acc;
    #pragma unroll
    for (int off = 32; off > 0; off >>= 1) {
        a_d += __shfl_down(a_d, off);
        t_d += __shfl_down(t_d, off);
    }
    if (tid == 0) {
        atomicAdd(&A[blockIdx.x & 63], a_d);
        atomicAdd(&T[r / H], t_d);
    }
}

__global__ void finalize(const unsigned int* __restrict__ dmax,
                         const double* __restrict__ A,
                         const double* __restrict__ T,
                         float* __restrict__ out) {
    if (threadIdx.x == 0) {
        double s = 0.0;
        for (int i = 0; i < 64; ++i) s += A[i];
        double st = 0.0;
        for (int i = 0; i < B * C; ++i)
            st += (double)__uint_as_float(dmax[i]) * T[i];
        out[0] = (float)((s - st) / ((double)C * (double)NTOT));
    }
}

extern "C" void kernel_launch(void* const* d_in, const int* in_sizes, int n_in,
                              void* d_out, int out_size, void* d_ws, size_t ws_size,
                              hipStream_t stream) {
    const float* outputs = (const float*)d_in[0];
    const int* targets = (const int*)d_in[1];
    float* out = (float*)d_out;

    float* g2 = (float*)d_ws;
    unsigned int* dmax = (unsigned int*)((char*)d_ws + DMAX_OFF);
    double* A = (double*)((char*)d_ws + A_OFF);
    double* T = (double*)((char*)d_ws + T_OFF);

    init_kernel<<<1, 64, 0, stream>>>(dmax, A, T);

    edt_vertical<<<(B * C * W) / 64, 64, 0, stream>>>(targets, g2);

    edt_horiz_fused<<<B * C * H, 64, 0, stream>>>(outputs, targets, g2, dmax, A, T);

    finalize<<<1, 64, 0, stream>>>(dmax, A, T, out);
}

// Round 3
// 126.207 us; speedup vs baseline: 4.6004x; 2.2540x over previous
//
#include <hip/hip_runtime.h>

#define B 8
#define C 4
#define H 384
#define W 384
#define HW (H * W)
#define CHW (C * H * W)
#define NTOT (B * CHW)      // 4,718,592
#define BIG2 589824         // 768^2 : reference's BIG cap, squared

// ---------------- ws layout ----------------
// @0   : 32 u32  dmax (float bits, per (b,c) slice)
// @128 : 64 dbl  A    (non-target loss partials, contention-spread)
// @640 : 32 dbl  T    (per-slice sum of softmax_c over target pixels)
#define A_OFF 128
#define T_OFF 640

__global__ void init_kernel(unsigned int* dmax, double* A, double* T) {
    int t = threadIdx.x;                 // 64 threads
    A[t] = 0.0;
    if (t < B * C) { dmax[t] = 0u; T[t] = 0.0; }
}

// min over set bits p of (p - lx)^2 ; m must be nonzero
__device__ __forceinline__ int nearest2(unsigned long long m, int lx) {
    unsigned long long right = m >> lx;          // bits p >= lx
    unsigned long long left  = m << (63 - lx);   // bits p <= lx
    int dR = right ? (int)__builtin_ctzll(right) : 999;
    int dL = left  ? (int)__builtin_clzll(left)  : 999;
    int d = min(dR, dL);
    return d * d;
}

// Exact Chebyshev-ring scan from global memory for the (essentially never
// taken) case where no feature was found within the staged 16-halo.
__device__ __attribute__((noinline))
int ring_fallback(const int* __restrict__ tg, int xa, int ya, int c, int best) {
    for (int d = 17; d * d < best; ++d) {
        int xlo = xa - d, xhi = xa + d, ylo = ya - d, yhi = ya + d;
        for (int xx = max(xlo, 0); xx <= min(xhi, W - 1); ++xx) {
            int ddx = xx - xa;
            int bb = ddx * ddx + d * d;
            if (bb < best) {
                if (ylo >= 0 && tg[ylo * W + xx] == c) best = bb;
                if (yhi < H && tg[yhi * W + xx] == c) best = min(best, bb);
            }
        }
        for (int yy = max(ylo + 1, 0); yy <= min(yhi - 1, H - 1); ++yy) {
            int ddy = yy - ya;
            int bb = ddy * ddy + d * d;
            if (bb < best) {
                if (xlo >= 0 && tg[yy * W + xlo] == c) best = bb;
                if (xhi < W && tg[yy * W + xhi] == c) best = min(best, bb);
            }
        }
    }
    return best;
}

// One block per 32x32 pixel tile of one image b. Stages 64x64 (16-halo)
// per-class bitmask rows in LDS; per pixel: softmax + adaptive nearest-
// feature search per class; fused loss + dmax reduction.
__global__ __launch_bounds__(256)
void dist_loss_kernel(const float* __restrict__ outputs,
                      const int* __restrict__ targets,
                      unsigned int* __restrict__ dmax,
                      double* __restrict__ A, double* __restrict__ T) {
    __shared__ unsigned long long rows[64][4];   // [tile row][class] bitmask
    __shared__ double sred[4][5];
    __shared__ float smax[4][4];

    int bid = blockIdx.x;
    int bx = bid % 12, by = (bid / 12) % 12, b = bid / 144;
    int x0 = bx * 32, y0 = by * 32;
    int tid = threadIdx.x, lane = tid & 63, wv = tid >> 6;
    const int* tg = targets + b * HW;

    // ---- stage: 64 rows, 4 class bitmasks each, via ballot ----
    for (int i = 0; i < 16; ++i) {
        int r = wv * 16 + i;
        int ya = y0 - 16 + r;
        int xa = x0 - 16 + lane;
        bool valid = (ya >= 0) && (ya < H) && (xa >= 0) && (xa < W);
        int yc = min(max(ya, 0), H - 1);
        int xc = min(max(xa, 0), W - 1);
        int tv = tg[yc * W + xc];
        unsigned long long m0 = __ballot(valid && tv == 0);
        unsigned long long m1 = __ballot(valid && tv == 1);
        unsigned long long m2 = __ballot(valid && tv == 2);
        unsigned long long m3 = __ballot(valid && tv == 3);
        if (lane == 0) {
            rows[r][0] = m0; rows[r][1] = m1; rows[r][2] = m2; rows[r][3] = m3;
        }
    }
    __syncthreads();

    double accA = 0.0;
    double accT[4] = {0.0, 0.0, 0.0, 0.0};
    float lmax[4] = {0.0f, 0.0f, 0.0f, 0.0f};

    for (int k = 0; k < 4; ++k) {
        int p = tid + 256 * k;
        int x = p & 31, y = p >> 5;
        int xa = x0 + x, ya = y0 + y;
        int lx = x + 16, ly = y + 16;
        int tv = tg[ya * W + xa];

        const float* ob = outputs + (size_t)b * CHW + ya * W + xa;
        float o0 = ob[0], o1 = ob[HW], o2 = ob[2 * HW], o3 = ob[3 * HW];
        float mx = fmaxf(fmaxf(o0, o1), fmaxf(o2, o3));
        float e0 = expf(o0 - mx), e1 = expf(o1 - mx);
        float e2 = expf(o2 - mx), e3 = expf(o3 - mx);
        float inv = 1.0f / (e0 + e1 + e2 + e3);
        float pr[4] = {e0 * inv, e1 * inv, e2 * inv, e3 * inv};

        #pragma unroll
        for (int c = 0; c < 4; ++c) {
            if (tv == c) {
                accT[c] += (double)pr[c];        // dt = 0 at feature pixels
            } else {
                int best = BIG2;
                unsigned long long m = rows[ly][c];
                if (m) best = nearest2(m, lx);
                for (int dy = 1; dy <= 16; ++dy) {
                    if (dy * dy >= best) break;
                    unsigned long long ma = rows[ly + dy][c];
                    unsigned long long mb = rows[ly - dy][c];
                    int b2 = dy * dy;
                    if (ma) best = min(best, b2 + nearest2(ma, lx));
                    if (mb) best = min(best, b2 + nearest2(mb, lx));
                }
                if (best > 289) best = ring_fallback(tg, xa, ya, c, best);
                float dt = sqrtf((float)best);   // exact int < 2^24 -> 1 rounding
                lmax[c] = fmaxf(lmax[c], dt);
                accA += (double)(pr[c] * dt);
            }
        }
    }

    // ---- wave reduce (64 lanes) ----
    #pragma unroll
    for (int off = 32; off > 0; off >>= 1) {
        accA += __shfl_down(accA, off);
        #pragma unroll
        for (int c = 0; c < 4; ++c) {
            accT[c] += __shfl_down(accT[c], off);
            lmax[c] = fmaxf(lmax[c], __shfl_down(lmax[c], off));
        }
    }
    if (lane == 0) {
        sred[wv][0] = accA;
        #pragma unroll
        for (int c = 0; c < 4; ++c) { sred[wv][1 + c] = accT[c]; smax[wv][c] = lmax[c]; }
    }
    __syncthreads();
    if (tid == 0) {
        double a = 0.0, t0 = 0.0, t1 = 0.0, t2 = 0.0, t3 = 0.0;
        float M[4] = {0.0f, 0.0f, 0.0f, 0.0f};
        #pragma unroll
        for (int w = 0; w < 4; ++w) {
            a += sred[w][0]; t0 += sred[w][1]; t1 += sred[w][2];
            t2 += sred[w][3]; t3 += sred[w][4];
            #pragma unroll
            for (int c = 0; c < 4; ++c) M[c] = fmaxf(M[c], smax[w][c]);
        }
        atomicAdd(&A[bid & 63], a);
        atomicAdd(&T[b * 4 + 0], t0);
        atomicAdd(&T[b * 4 + 1], t1);
        atomicAdd(&T[b * 4 + 2], t2);
        atomicAdd(&T[b * 4 + 3], t3);
        #pragma unroll
        for (int c = 0; c < 4; ++c)
            atomicMax(&dmax[b * 4 + c], __float_as_uint(M[c]));
    }
}

__global__ void finalize(const unsigned int* __restrict__ dmax,
                         const double* __restrict__ A,
                         const double* __restrict__ T,
                         float* __restrict__ out) {
    if (threadIdx.x == 0) {
        double s = 0.0;
        for (int i = 0; i < 64; ++i) s += A[i];
        double st = 0.0;
        for (int i = 0; i < B * C; ++i)
            st += (double)__uint_as_float(dmax[i]) * T[i];
        out[0] = (float)((s - st) / ((double)C * (double)NTOT));
    }
}

extern "C" void kernel_launch(void* const* d_in, const int* in_sizes, int n_in,
                              void* d_out, int out_size, void* d_ws, size_t ws_size,
                              hipStream_t stream) {
    const float* outputs = (const float*)d_in[0];
    const int* targets = (const int*)d_in[1];
    float* out = (float*)d_out;

    unsigned int* dmax = (unsigned int*)d_ws;
    double* A = (double*)((char*)d_ws + A_OFF);
    double* T = (double*)((char*)d_ws + T_OFF);

    init_kernel<<<1, 64, 0, stream>>>(dmax, A, T);

    dist_loss_kernel<<<12 * 12 * B, 256, 0, stream>>>(outputs, targets, dmax, A, T);

    finalize<<<1, 64, 0, stream>>>(dmax, A, T, out);
}

// Round 4
// 109.845 us; speedup vs baseline: 5.2856x; 1.1490x over previous
//
#include <hip/hip_runtime.h>

#define B 8
#define C 4
#define H 384
#define W 384
#define HW (H * W)
#define CHW (C * H * W)
#define NTOT (B * CHW)        // 4,718,592
#define BIG2 589824           // 768^2, reference's BIG cap squared
#define TPI 576               // tiles per image (24x24 of 16x16)
#define NBLK (B * TPI)        // 4608
#define PSTR 12               // floats per block partial record

// min over set bits p of (p - lx)^2 ; 999 sentinel if empty side.
// lx in [16,32) so all bits p<=lx live in the low 32 bits (shl = 31-lx).
__device__ __forceinline__ int nearest2(unsigned long long m, int lx, int shl) {
    unsigned long long right = m >> lx;
    int dR = right ? (int)__builtin_ctzll(right) : 999;
    unsigned int leftb = ((unsigned int)m) << shl;
    int dL = leftb ? (int)__builtin_clz(leftb) : 999;
    int d = min(dR, dL);
    return d * d;
}

// Exact Chebyshev-ring global-memory scan (essentially never taken).
__device__ __attribute__((noinline))
int ring_fallback(const int* __restrict__ tg, int xa, int ya, int c, int best) {
    for (int d = 17; d * d < best; ++d) {
        int xlo = xa - d, xhi = xa + d, ylo = ya - d, yhi = ya + d;
        for (int xx = max(xlo, 0); xx <= min(xhi, W - 1); ++xx) {
            int ddx = xx - xa;
            int bb = ddx * ddx + d * d;
            if (bb < best) {
                if (ylo >= 0 && tg[ylo * W + xx] == c) best = bb;
                if (yhi < H && tg[yhi * W + xx] == c) best = min(best, bb);
            }
        }
        for (int yy = max(ylo + 1, 0); yy <= min(yhi - 1, H - 1); ++yy) {
            int ddy = yy - ya;
            int bb = ddy * ddy + d * d;
            if (bb < best) {
                if (xlo >= 0 && tg[yy * W + xlo] == c) best = bb;
                if (xhi < W && tg[yy * W + xhi] == c) best = min(best, bb);
            }
        }
    }
    return best;
}

// One 256-thread block per 16x16 tile. Stage 48x64 per-class bitmasks,
// pre-OR the +-dy row pairs, then per pixel: 8 broadcast b128 LDS reads,
// 16 branchless bit-scans, softmax, fused partial reduction.
__global__ __launch_bounds__(256)
void dist_loss_kernel(const float* __restrict__ outputs,
                      const int* __restrict__ targets,
                      float* __restrict__ parts) {
    __shared__ unsigned long long rowsm[48][4];   // raw class masks (halo 16)
    __shared__ unsigned long long big[16 * 18];   // [ly16][c][lvl0..3], 144B/row pad
    __shared__ float sred[4][9];

    int bid = blockIdx.x;
    int bx = bid % 24, by = (bid / 24) % 24, b = bid / TPI;
    int x0 = bx * 16, y0 = by * 16;
    int tid = threadIdx.x, lane = tid & 63, wv = tid >> 6;
    const int* tg = targets + b * HW;

    // ---- stage 48 rows of class bitmasks via ballot ----
    for (int i = 0; i < 12; ++i) {
        int r = i * 4 + wv;
        int ya = y0 - 16 + r, xa = x0 - 16 + lane;
        bool valid = (ya >= 0) && (ya < H) && (xa >= 0) && (xa < W);
        int yc = min(max(ya, 0), H - 1), xc = min(max(xa, 0), W - 1);
        int tv = tg[yc * W + xc];
        unsigned long long m0 = __ballot(valid && tv == 0);
        unsigned long long m1 = __ballot(valid && tv == 1);
        unsigned long long m2 = __ballot(valid && tv == 2);
        unsigned long long m3 = __ballot(valid && tv == 3);
        if (lane == 0) {
            rowsm[r][0] = m0; rowsm[r][1] = m1; rowsm[r][2] = m2; rowsm[r][3] = m3;
        }
    }
    __syncthreads();

    // ---- pre-OR +-dy pairs: big[ly][c][lvl] ; lvl0 = row itself ----
    if (tid < 64) {
        int ly16 = tid >> 2, c = tid & 3;
        big[ly16 * 18 + c * 4] = rowsm[16 + ly16][c];
    } else {
        int idx = tid - 64;                 // 192 threads
        int ly16 = idx / 12, rem = idx % 12;
        int lvl = 1 + (rem >> 2), c = rem & 3;
        big[ly16 * 18 + c * 4 + lvl] =
            rowsm[16 + ly16 - lvl][c] | rowsm[16 + ly16 + lvl][c];
    }
    __syncthreads();

    // ---- per-pixel fused loss ----
    int x = tid & 15, y = tid >> 4;
    int xa = x0 + x, ya = y0 + y;
    int lx = x + 16, shl = 31 - lx, ly = y + 16;

    const float* ob = outputs + (size_t)b * CHW + ya * W + xa;
    float o0 = ob[0], o1 = ob[HW], o2 = ob[2 * HW], o3 = ob[3 * HW];
    float mx = fmaxf(fmaxf(o0, o1), fmaxf(o2, o3));
    float e0 = expf(o0 - mx), e1 = expf(o1 - mx);
    float e2 = expf(o2 - mx), e3 = expf(o3 - mx);
    float inv = 1.0f / (e0 + e1 + e2 + e3);
    float pr[4] = {e0 * inv, e1 * inv, e2 * inv, e3 * inv};

    float red[9];
    red[0] = 0.0f;
    #pragma unroll
    for (int c = 0; c < 4; ++c) {
        const ulonglong2* pp = (const ulonglong2*)&big[y * 18 + c * 4];
        ulonglong2 v0 = pp[0], v1 = pp[1];
        int n0 = nearest2(v0.x, lx, shl);       // dy = 0
        int n1 = nearest2(v0.y, lx, shl) + 1;   // |dy| = 1
        int n2 = nearest2(v1.x, lx, shl) + 4;   // |dy| = 2
        int n3 = nearest2(v1.y, lx, shl) + 9;   // |dy| = 3
        int best = min(min(n0, n1), min(n2, n3));
        if (best > 16) {                        // exact only if best <= 16
            for (int dy = 4; dy <= 16 && dy * dy < best; ++dy) {
                unsigned long long m = rowsm[ly + dy][c] | rowsm[ly - dy][c];
                if (m) best = min(best, dy * dy + nearest2(m, lx, shl));
            }
            if (best > 289) {                   // beyond staged dx/dy coverage
                best = min(best, BIG2);
                best = ring_fallback(tg, xa, ya, c, best);
            }
        }
        float dt = sqrtf((float)best);          // exact int < 2^24
        red[0] += pr[c] * dt;                   // target class: best==0
        red[1 + c] = ((v0.x >> lx) & 1ull) ? pr[c] : 0.0f;  // T contribution
        red[5 + c] = dt;                        // slice max candidate
    }

    // ---- block reduce: red[0..4] sum, red[5..8] max ----
    #pragma unroll
    for (int off = 32; off > 0; off >>= 1) {
        #pragma unroll
        for (int j = 0; j < 5; ++j) red[j] += __shfl_down(red[j], off);
        #pragma unroll
        for (int j = 5; j < 9; ++j) red[j] = fmaxf(red[j], __shfl_down(red[j], off));
    }
    if (lane == 0) {
        #pragma unroll
        for (int j = 0; j < 9; ++j) sred[wv][j] = red[j];
    }
    __syncthreads();
    if (tid == 0) {
        float o[9];
        #pragma unroll
        for (int j = 0; j < 9; ++j) o[j] = sred[0][j];
        #pragma unroll
        for (int w = 1; w < 4; ++w) {
            #pragma unroll
            for (int j = 0; j < 5; ++j) o[j] += sred[w][j];
            #pragma unroll
            for (int j = 5; j < 9; ++j) o[j] = fmaxf(o[j], sred[w][j]);
        }
        #pragma unroll
        for (int j = 0; j < 9; ++j) parts[bid * PSTR + j] = o[j];
    }
}

// Single block: reduce 4608 block partials -> scalar loss.
__global__ __launch_bounds__(256)
void finalize(const float* __restrict__ parts, float* __restrict__ out) {
    __shared__ double asum[4];
    __shared__ double Tsh[32];
    __shared__ float Msh[32];
    int tid = threadIdx.x, lane = tid & 63, wv = tid >> 6;

    // total A
    double a = 0.0;
    for (int i = tid; i < NBLK; i += 256) a += (double)parts[i * PSTR];
    #pragma unroll
    for (int off = 32; off > 0; off >>= 1) a += __shfl_down(a, off);
    if (lane == 0) asum[wv] = a;

    // per-slice T sum and M max: wave wv handles slices wv*8 .. wv*8+7
    for (int k = 0; k < 8; ++k) {
        int s = wv * 8 + k;
        int b = s >> 2, c = s & 3;
        double ts = 0.0;
        float ms = 0.0f;
        for (int i = lane; i < TPI; i += 64) {
            int blk = b * TPI + i;
            ts += (double)parts[blk * PSTR + 1 + c];
            ms = fmaxf(ms, parts[blk * PSTR + 5 + c]);
        }
        #pragma unroll
        for (int off = 32; off > 0; off >>= 1) {
            ts += __shfl_down(ts, off);
            ms = fmaxf(ms, __shfl_down(ms, off));
        }
        if (lane == 0) { Tsh[s] = ts; Msh[s] = ms; }
    }
    __syncthreads();
    if (tid == 0) {
        double A = asum[0] + asum[1] + asum[2] + asum[3];
        double st = 0.0;
        for (int s = 0; s < 32; ++s) st += (double)Msh[s] * Tsh[s];
        out[0] = (float)((A - st) / ((double)C * (double)NTOT));
    }
}

extern "C" void kernel_launch(void* const* d_in, const int* in_sizes, int n_in,
                              void* d_out, int out_size, void* d_ws, size_t ws_size,
                              hipStream_t stream) {
    const float* outputs = (const float*)d_in[0];
    const int* targets = (const int*)d_in[1];
    float* out = (float*)d_out;
    float* parts = (float*)d_ws;   // NBLK * PSTR floats = 221 KB

    dist_loss_kernel<<<NBLK, 256, 0, stream>>>(outputs, targets, parts);
    finalize<<<1, 256, 0, stream>>>(parts, out);
}

// Round 5
// 98.572 us; speedup vs baseline: 5.8901x; 1.1144x over previous
//
#include <hip/hip_runtime.h>

#define B 8
#define C 4
#define H 384
#define W 384
#define HW (H * W)
#define CHW (C * H * W)
#define NTOT (B * CHW)        // 4,718,592
#define BIG2 589824           // 768^2, reference's BIG cap squared
#define TPI 288               // tiles per image (12x24 of 32x16)
#define NBLK (B * TPI)        // 2304
#define PSTR 12               // floats per block partial record
#define LOG2E 1.44269504088896340736f

// min over set bits p of (p - lx)^2 ; 999 sentinel if empty side. lx in [16,48).
__device__ __forceinline__ int nearest2(unsigned long long m, int lx, int shl) {
    unsigned long long right = m >> lx;
    int dR = right ? (int)__builtin_ctzll(right) : 999;
    unsigned long long leftb = m << shl;            // shl = 63 - lx
    int dL = leftb ? (int)__builtin_clzll(leftb) : 999;
    int d = min(dR, dL);
    return d * d;
}

// Exact Chebyshev-ring global-memory scan (essentially never taken).
__device__ __attribute__((noinline))
int ring_fallback(const int* __restrict__ tg, int xa, int ya, int c, int best) {
    for (int d = 17; d * d < best; ++d) {
        int xlo = xa - d, xhi = xa + d, ylo = ya - d, yhi = ya + d;
        for (int xx = max(xlo, 0); xx <= min(xhi, W - 1); ++xx) {
            int ddx = xx - xa;
            int bb = ddx * ddx + d * d;
            if (bb < best) {
                if (ylo >= 0 && tg[ylo * W + xx] == c) best = bb;
                if (yhi < H && tg[yhi * W + xx] == c) best = min(best, bb);
            }
        }
        for (int yy = max(ylo + 1, 0); yy <= min(yhi - 1, H - 1); ++yy) {
            int ddy = yy - ya;
            int bb = ddy * ddy + d * d;
            if (bb < best) {
                if (xlo >= 0 && tg[yy * W + xlo] == c) best = bb;
                if (xhi < W && tg[yy * W + xhi] == c) best = min(best, bb);
            }
        }
    }
    return best;
}

// One 256-thread block per 32x16 tile (2 px/thread). Stage 48x64 per-class
// bitmasks via ballot, pre-OR +-dy row pairs (1 write/thread), then per
// pixel: 8 broadcast b128 LDS reads + 16 branchless bit-scans + softmax.
__global__ __launch_bounds__(256)
void dist_loss_kernel(const float* __restrict__ outputs,
                      const int* __restrict__ targets,
                      float* __restrict__ parts) {
    __shared__ unsigned long long rowsm[48][4];   // raw class masks (y halo 16)
    __shared__ unsigned long long big[16 * 18];   // [y][c][lvl0..3], 144B/row pad
    __shared__ float sred[4][9];

    int bid = blockIdx.x;
    int bx = bid % 12, by = (bid / 12) % 24, b = bid / TPI;
    int x0 = bx * 32, y0 = by * 16;
    int tid = threadIdx.x, lane = tid & 63, wv = tid >> 6;
    const int* tg = targets + b * HW;

    // ---- stage 48 rows of class bitmasks via ballot ----
    for (int i = 0; i < 12; ++i) {
        int r = i * 4 + wv;
        int ya = y0 - 16 + r, xa = x0 - 16 + lane;
        bool valid = (ya >= 0) && (ya < H) && (xa >= 0) && (xa < W);
        int yc = min(max(ya, 0), H - 1), xc = min(max(xa, 0), W - 1);
        int tv = tg[yc * W + xc];
        unsigned long long m0 = __ballot(valid && tv == 0);
        unsigned long long m1 = __ballot(valid && tv == 1);
        unsigned long long m2 = __ballot(valid && tv == 2);
        unsigned long long m3 = __ballot(valid && tv == 3);
        if (lane == 0) {
            rowsm[r][0] = m0; rowsm[r][1] = m1; rowsm[r][2] = m2; rowsm[r][3] = m3;
        }
    }
    __syncthreads();

    // ---- pre-OR +-dy pairs: exactly one u64 per thread ----
    {
        int yy = tid >> 4, c = (tid >> 2) & 3, lvl = tid & 3;
        unsigned long long v = (lvl == 0)
            ? rowsm[16 + yy][c]
            : (rowsm[16 + yy - lvl][c] | rowsm[16 + yy + lvl][c]);
        big[yy * 18 + c * 4 + lvl] = v;
    }
    __syncthreads();

    // ---- per-pixel fused loss: 2 pixels per thread ----
    int x = tid & 31, yb = tid >> 5;              // yb in [0,8)
    int lx = x + 16, shl = 63 - lx;

    float red[9];
    #pragma unroll
    for (int j = 0; j < 9; ++j) red[j] = 0.0f;

    #pragma unroll
    for (int k = 0; k < 2; ++k) {
        int y = yb + 8 * k;
        int xa = x0 + x, ya = y0 + y, ly = y + 16;

        const float* ob = outputs + (size_t)b * CHW + ya * W + xa;
        float e0 = exp2f(ob[0] * LOG2E);
        float e1 = exp2f(ob[HW] * LOG2E);
        float e2 = exp2f(ob[2 * HW] * LOG2E);
        float e3 = exp2f(ob[3 * HW] * LOG2E);
        float inv = 1.0f / (e0 + e1 + e2 + e3);
        float pr[4] = {e0 * inv, e1 * inv, e2 * inv, e3 * inv};

        #pragma unroll
        for (int c = 0; c < 4; ++c) {
            const ulonglong2* pp = (const ulonglong2*)&big[y * 18 + c * 4];
            ulonglong2 v0 = pp[0], v1 = pp[1];
            int n0 = nearest2(v0.x, lx, shl);       // dy = 0
            int n1 = nearest2(v0.y, lx, shl) + 1;   // |dy| = 1
            int n2 = nearest2(v1.x, lx, shl) + 4;   // |dy| = 2
            int n3 = nearest2(v1.y, lx, shl) + 9;   // |dy| = 3
            int best = min(min(n0, n1), min(n2, n3));
            if (best > 16) {                        // rare: exact extension
                for (int dy = 4; dy <= 16 && dy * dy < best; ++dy) {
                    unsigned long long m = rowsm[ly + dy][c] | rowsm[ly - dy][c];
                    if (m) best = min(best, dy * dy + nearest2(m, lx, shl));
                }
                if (best > 289) {
                    best = min(best, BIG2);
                    best = ring_fallback(tg, xa, ya, c, best);
                }
            }
            float dt = sqrtf((float)best);          // exact int < 2^24
            red[0] += pr[c] * dt;                   // target class: dt==0
            if ((v0.x >> lx) & 1ull) red[1 + c] += pr[c];   // T contribution
            red[5 + c] = fmaxf(red[5 + c], dt);     // slice max candidate
        }
    }

    // ---- block reduce: red[0..4] sum, red[5..8] max ----
    #pragma unroll
    for (int off = 32; off > 0; off >>= 1) {
        #pragma unroll
        for (int j = 0; j < 5; ++j) red[j] += __shfl_down(red[j], off);
        #pragma unroll
        for (int j = 5; j < 9; ++j) red[j] = fmaxf(red[j], __shfl_down(red[j], off));
    }
    if (lane == 0) {
        #pragma unroll
        for (int j = 0; j < 9; ++j) sred[wv][j] = red[j];
    }
    __syncthreads();
    if (tid == 0) {
        float o[9];
        #pragma unroll
        for (int j = 0; j < 9; ++j) o[j] = sred[0][j];
        #pragma unroll
        for (int w = 1; w < 4; ++w) {
            #pragma unroll
            for (int j = 0; j < 5; ++j) o[j] += sred[w][j];
            #pragma unroll
            for (int j = 5; j < 9; ++j) o[j] = fmaxf(o[j], sred[w][j]);
        }
        #pragma unroll
        for (int j = 0; j < 9; ++j) parts[bid * PSTR + j] = o[j];
    }
}

// Single block: reduce 2304 block partials -> scalar loss.
__global__ __launch_bounds__(256)
void finalize(const float* __restrict__ parts, float* __restrict__ out) {
    __shared__ double asum[4];
    __shared__ double Tsh[32];
    __shared__ float Msh[32];
    int tid = threadIdx.x, lane = tid & 63, wv = tid >> 6;

    double a = 0.0;
    for (int i = tid; i < NBLK; i += 256) a += (double)parts[i * PSTR];
    #pragma unroll
    for (int off = 32; off > 0; off >>= 1) a += __shfl_down(a, off);
    if (lane == 0) asum[wv] = a;

    for (int k = 0; k < 8; ++k) {
        int s = wv * 8 + k;
        int b = s >> 2, c = s & 3;
        double ts = 0.0;
        float ms = 0.0f;
        for (int i = lane; i < TPI; i += 64) {
            int blk = b * TPI + i;
            ts += (double)parts[blk * PSTR + 1 + c];
            ms = fmaxf(ms, parts[blk * PSTR + 5 + c]);
        }
        #pragma unroll
        for (int off = 32; off > 0; off >>= 1) {
            ts += __shfl_down(ts, off);
            ms = fmaxf(ms, __shfl_down(ms, off));
        }
        if (lane == 0) { Tsh[s] = ts; Msh[s] = ms; }
    }
    __syncthreads();
    if (tid == 0) {
        double A = asum[0] + asum[1] + asum[2] + asum[3];
        double st = 0.0;
        for (int s = 0; s < 32; ++s) st += (double)Msh[s] * Tsh[s];
        out[0] = (float)((A - st) / ((double)C * (double)NTOT));
    }
}

extern "C" void kernel_launch(void* const* d_in, const int* in_sizes, int n_in,
                              void* d_out, int out_size, void* d_ws, size_t ws_size,
                              hipStream_t stream) {
    const float* outputs = (const float*)d_in[0];
    const int* targets = (const int*)d_in[1];
    float* out = (float*)d_out;
    float* parts = (float*)d_ws;   // NBLK * PSTR floats = 110 KB

    dist_loss_kernel<<<NBLK, 256, 0, stream>>>(outputs, targets, parts);
    finalize<<<1, 256, 0, stream>>>(parts, out);
}

// Round 6
// 97.546 us; speedup vs baseline: 5.9521x; 1.0105x over previous
//
#include <hip/hip_runtime.h>

#define B 8
#define C 4
#define H 384
#define W 384
#define HW (H * W)
#define CHW (C * H * W)
#define NTOT (B * CHW)        // 4,718,592
#define BIG2 589824           // 768^2, reference's BIG cap squared
#define TPI 144               // tiles per image (12x12 of 32x32)
#define NBLK (B * TPI)        // 1152
#define PSTR 12               // floats per block partial record
#define LOG2E 1.44269504088896340736f

// min over set bits p of (p - lx)^2 ; 999 sentinel if empty side. lx in [16,48).
__device__ __forceinline__ int nearest2(unsigned long long m, int lx, int shl) {
    unsigned long long right = m >> lx;
    int dR = right ? (int)__builtin_ctzll(right) : 999;
    unsigned long long leftb = m << shl;            // shl = 63 - lx
    int dL = leftb ? (int)__builtin_clzll(leftb) : 999;
    int d = min(dR, dL);
    return d * d;
}

// Exact Chebyshev-ring global-memory scan (essentially never taken).
__device__ __attribute__((noinline))
int ring_fallback(const int* __restrict__ tg, int xa, int ya, int c, int best) {
    for (int d = 17; d * d < best; ++d) {
        int xlo = xa - d, xhi = xa + d, ylo = ya - d, yhi = ya + d;
        for (int xx = max(xlo, 0); xx <= min(xhi, W - 1); ++xx) {
            int ddx = xx - xa;
            int bb = ddx * ddx + d * d;
            if (bb < best) {
                if (ylo >= 0 && tg[ylo * W + xx] == c) best = bb;
                if (yhi < H && tg[yhi * W + xx] == c) best = min(best, bb);
            }
        }
        for (int yy = max(ylo + 1, 0); yy <= min(yhi - 1, H - 1); ++yy) {
            int ddy = yy - ya;
            int bb = ddy * ddy + d * d;
            if (bb < best) {
                if (xlo >= 0 && tg[yy * W + xlo] == c) best = bb;
                if (xhi < W && tg[yy * W + xhi] == c) best = min(best, bb);
            }
        }
    }
    return best;
}

// One 256-thread block per 32x32 tile (4 px/thread). Stage 64x64 per-class
// bitmasks via ballot (uniform fast path for interior tiles), pre-OR +-dy
// row pairs, then per pixel: 2 broadcast b128 LDS reads/class + branchless
// bit-scans + softmax; one 9-value block reduce per 1024 pixels.
__global__ __launch_bounds__(256)
void dist_loss_kernel(const float* __restrict__ outputs,
                      const int* __restrict__ targets,
                      float* __restrict__ parts) {
    __shared__ unsigned long long rowsm[64][4];   // raw class masks (y halo 16)
    __shared__ unsigned long long big[32 * 18];   // [y][c][lvl0..3], 144B/row pad
    __shared__ float sred[4][9];

    int bid = blockIdx.x;
    int bx = bid % 12, by = (bid / 12) % 12, b = bid / TPI;
    int x0 = bx * 32, y0 = by * 32;
    int tid = threadIdx.x, lane = tid & 63, wv = tid >> 6;
    const int* tg = targets + b * HW;

    // ---- stage 64 rows of class bitmasks via ballot ----
    bool edge = (bx == 0) | (bx == 11) | (by == 0) | (by == 11);
    if (!edge) {
        const int* tp = tg + (y0 - 16 + wv) * W + (x0 - 16 + lane);
        for (int i = 0; i < 16; ++i) {
            int r = i * 4 + wv;
            int tv = tp[i * 4 * W];
            unsigned long long m0 = __ballot(tv == 0);
            unsigned long long m1 = __ballot(tv == 1);
            unsigned long long m2 = __ballot(tv == 2);
            unsigned long long m3 = __ballot(tv == 3);
            if (lane == 0) {
                rowsm[r][0] = m0; rowsm[r][1] = m1;
                rowsm[r][2] = m2; rowsm[r][3] = m3;
            }
        }
    } else {
        for (int i = 0; i < 16; ++i) {
            int r = i * 4 + wv;
            int ya = y0 - 16 + r, xa = x0 - 16 + lane;
            bool valid = (ya >= 0) & (ya < H) & (xa >= 0) & (xa < W);
            int yc = min(max(ya, 0), H - 1), xc = min(max(xa, 0), W - 1);
            int tv = tg[yc * W + xc];
            unsigned long long m0 = __ballot(valid && tv == 0);
            unsigned long long m1 = __ballot(valid && tv == 1);
            unsigned long long m2 = __ballot(valid && tv == 2);
            unsigned long long m3 = __ballot(valid && tv == 3);
            if (lane == 0) {
                rowsm[r][0] = m0; rowsm[r][1] = m1;
                rowsm[r][2] = m2; rowsm[r][3] = m3;
            }
        }
    }
    __syncthreads();

    // ---- pre-OR +-dy pairs: two u64 per thread ----
    #pragma unroll
    for (int q = 0; q < 2; ++q) {
        int idx = tid + 256 * q;            // 0..511
        int yy = idx >> 4, c = (idx >> 2) & 3, lvl = idx & 3;
        unsigned long long v = (lvl == 0)
            ? rowsm[16 + yy][c]
            : (rowsm[16 + yy - lvl][c] | rowsm[16 + yy + lvl][c]);
        big[yy * 18 + c * 4 + lvl] = v;
    }
    __syncthreads();

    // ---- per-pixel fused loss: 4 pixels per thread ----
    int x = tid & 31, yb = tid >> 5;              // yb in [0,8)
    int lx = x + 16, shl = 63 - lx;

    float red[9];
    #pragma unroll
    for (int j = 0; j < 9; ++j) red[j] = 0.0f;

    #pragma unroll
    for (int k = 0; k < 4; ++k) {
        int y = yb + 8 * k;
        int xa = x0 + x, ya = y0 + y, ly = y + 16;

        const float* ob = outputs + (size_t)b * CHW + ya * W + xa;
        float e0 = exp2f(ob[0] * LOG2E);
        float e1 = exp2f(ob[HW] * LOG2E);
        float e2 = exp2f(ob[2 * HW] * LOG2E);
        float e3 = exp2f(ob[3 * HW] * LOG2E);
        float inv = 1.0f / (e0 + e1 + e2 + e3);
        float pr[4] = {e0 * inv, e1 * inv, e2 * inv, e3 * inv};

        #pragma unroll
        for (int c = 0; c < 4; ++c) {
            const ulonglong2* pp = (const ulonglong2*)&big[y * 18 + c * 4];
            ulonglong2 v0 = pp[0], v1 = pp[1];
            int n0 = nearest2(v0.x, lx, shl);       // dy = 0
            int n1 = nearest2(v0.y, lx, shl) + 1;   // |dy| = 1
            int n2 = nearest2(v1.x, lx, shl) + 4;   // |dy| = 2
            int n3 = nearest2(v1.y, lx, shl) + 9;   // |dy| = 3
            int best = min(min(n0, n1), min(n2, n3));
            if (best > 16) {                        // rare: exact extension
                for (int dy = 4; dy <= 16 && dy * dy < best; ++dy) {
                    unsigned long long m = rowsm[ly + dy][c] | rowsm[ly - dy][c];
                    if (m) best = min(best, dy * dy + nearest2(m, lx, shl));
                }
                if (best > 289) {
                    best = min(best, BIG2);
                    best = ring_fallback(tg, xa, ya, c, best);
                }
            }
            float dt = sqrtf((float)best);          // exact int < 2^24
            red[0] += pr[c] * dt;                   // target class: dt==0
            if ((v0.x >> lx) & 1ull) red[1 + c] += pr[c];   // T contribution
            red[5 + c] = fmaxf(red[5 + c], dt);     // slice max candidate
        }
    }

    // ---- block reduce: red[0..4] sum, red[5..8] max ----
    #pragma unroll
    for (int off = 32; off > 0; off >>= 1) {
        #pragma unroll
        for (int j = 0; j < 5; ++j) red[j] += __shfl_down(red[j], off);
        #pragma unroll
        for (int j = 5; j < 9; ++j) red[j] = fmaxf(red[j], __shfl_down(red[j], off));
    }
    if (lane == 0) {
        #pragma unroll
        for (int j = 0; j < 9; ++j) sred[wv][j] = red[j];
    }
    __syncthreads();
    if (tid == 0) {
        float o[9];
        #pragma unroll
        for (int j = 0; j < 9; ++j) o[j] = sred[0][j];
        #pragma unroll
        for (int w = 1; w < 4; ++w) {
            #pragma unroll
            for (int j = 0; j < 5; ++j) o[j] += sred[w][j];
            #pragma unroll
            for (int j = 5; j < 9; ++j) o[j] = fmaxf(o[j], sred[w][j]);
        }
        #pragma unroll
        for (int j = 0; j < 9; ++j) parts[bid * PSTR + j] = o[j];
    }
}

// Single block: reduce 1152 block partials -> scalar loss.
__global__ __launch_bounds__(256)
void finalize(const float* __restrict__ parts, float* __restrict__ out) {
    __shared__ double asum[4];
    __shared__ double Tsh[32];
    __shared__ float Msh[32];
    int tid = threadIdx.x, lane = tid & 63, wv = tid >> 6;

    double a = 0.0;
    for (int i = tid; i < NBLK; i += 256) a += (double)parts[i * PSTR];
    #pragma unroll
    for (int off = 32; off > 0; off >>= 1) a += __shfl_down(a, off);
    if (lane == 0) asum[wv] = a;

    for (int k = 0; k < 8; ++k) {
        int s = wv * 8 + k;
        int b = s >> 2, c = s & 3;
        double ts = 0.0;
        float ms = 0.0f;
        for (int i = lane; i < TPI; i += 64) {
            int blk = b * TPI + i;
            ts += (double)parts[blk * PSTR + 1 + c];
            ms = fmaxf(ms, parts[blk * PSTR + 5 + c]);
        }
        #pragma unroll
        for (int off = 32; off > 0; off >>= 1) {
            ts += __shfl_down(ts, off);
            ms = fmaxf(ms, __shfl_down(ms, off));
        }
        if (lane == 0) { Tsh[s] = ts; Msh[s] = ms; }
    }
    __syncthreads();
    if (tid == 0) {
        double A = asum[0] + asum[1] + asum[2] + asum[3];
        double st = 0.0;
        for (int s = 0; s < 32; ++s) st += (double)Msh[s] * Tsh[s];
        out[0] = (float)((A - st) / ((double)C * (double)NTOT));
    }
}

extern "C" void kernel_launch(void* const* d_in, const int* in_sizes, int n_in,
                              void* d_out, int out_size, void* d_ws, size_t ws_size,
                              hipStream_t stream) {
    const float* outputs = (const float*)d_in[0];
    const int* targets = (const int*)d_in[1];
    float* out = (float*)d_out;
    float* parts = (float*)d_ws;   // NBLK * PSTR floats = 55 KB

    dist_loss_kernel<<<NBLK, 256, 0, stream>>>(outputs, targets, parts);
    finalize<<<1, 256, 0, stream>>>(parts, out);
}